// Round 5
// baseline (540.278 us; speedup 1.0000x reference)
//
#include <hip/hip_runtime.h>
#include <math.h>

// Quantum circuit sim, 20 qubits, 4 layers, batch 16, purely-real f32 state.
// Element bit Ek <-> qubit q = 19-k. 7 fused passes (R A F L A F L), each a
// 14-bit window kernel; M/P/Q bit-permuted inter-pass layouts keep every
// global access a dense float4. R5: each block pipelines 2 chunks (grid 512),
// prefetching chunk1's loads into float4 regs across chunk0's barrier phases.

__global__ void cs_kernel(const float* __restrict__ theta, float2* __restrict__ cs) {
    int i = threadIdx.x;
    if (i < 80) {
        float s, c;
        sincosf(theta[i] * 0.5f, &s, &c);
        cs[i] = make_float2(c, s);
    }
}

#define RYT_(TBL, MASK, Q) { float2 _sc = (TBL)[(Q)]; float _c = _sc.x, _s = _sc.y; \
  _Pragma("unroll") for (int _m = 0; _m < 32; ++_m) if (!(_m & (MASK))) { \
    float _a = v[_m], _b = v[_m | (MASK)]; \
    v[_m] = _c*_a - _s*_b; v[_m | (MASK)] = _s*_a + _c*_b; } }

#define CX_(CM, TM) { _Pragma("unroll") for (int _m = 0; _m < 32; ++_m) \
  if ((_m & (CM)) && !(_m & (TM))) { float _t = v[_m]; v[_m] = v[_m|(TM)]; v[_m|(TM)] = _t; } }

#define CXI_(COND, TM) { if (COND) { _Pragma("unroll") for (int _m = 0; _m < 32; ++_m) \
  if (!(_m & (TM))) { float _t = v[_m]; v[_m] = v[_m|(TM)]; v[_m|(TM)] = _t; } } }

#define SWAPIN_ { __syncthreads(); _Pragma("unroll") \
  for (int _i = 0; _i < 8; ++_i) { v[4*_i] = u4[_i].x; v[4*_i+1] = u4[_i].y; \
    v[4*_i+2] = u4[_i].z; v[4*_i+3] = u4[_i].w; } }

__device__ __forceinline__ int mixR(int n) {
    return ((n >> 5) & 31) ^ ((n >> 10) & 1);
}
__device__ __forceinline__ int mixA(int n) {
    return ((n >> 5) & 31) ^ ((n >> 10) & 1) ^ (((n >> 11) & 1) << 3)
         ^ (((n >> 12) & 1) << 4) ^ (((n >> 13) & 1) << 4);
}
__device__ __forceinline__ int mixF(int n) {
    return ((n >> 5) & 31) ^ (((n >> 10) & 1) << 1) ^ (((n >> 11) & 1) << 2)
         ^ (((n >> 12) & 1) << 3) ^ (((n >> 13) & 1) << 4);
}
__device__ __forceinline__ int mixL(int n) {
    return ((n >> 5) & 31) ^ (((n >> 10) & 1) << 4) ^ (((n >> 11) & 1) << 2)
         ^ (((n >> 12) & 1) << 3) ^ (((n >> 13) & 1) << 4);
}

// ---------------- Pass R: std -> M, RY on E13..E0 (layer 0) ----------------
__global__ __launch_bounds__(512, 4) void pass_R(
    const float4* __restrict__ src, float4* __restrict__ dst,
    const float2* __restrict__ cs)
{
    __shared__ float lds[16384];
    const float2* csl = cs;
    int t = threadIdx.x;
    float v[32];
    float4 u4[8];

    int lof = (((t >> 6) & 3) << 6) + (((t >> 8) & 1) << 11) + (t & 63);
    {   int blk = blockIdx.x;
        int base = ((blk >> 6) << 18) + ((blk & 63) << 12);
#pragma unroll
        for (int i = 0; i < 8; ++i) {
            float4 w = src[base + (i << 8) + lof];
            v[4*i] = w.x; v[4*i+1] = w.y; v[4*i+2] = w.z; v[4*i+3] = w.w;
        } }

#pragma unroll
    for (int cc = 0; cc < 2; ++cc) {
        int blk = blockIdx.x + (cc << 9);
        int base = ((blk >> 6) << 18) + ((blk & 63) << 12);
        if (cc == 0) {                           // prefetch chunk1 (stays in u4)
            int blk1 = blockIdx.x + 512;
            int base1 = ((blk1 >> 6) << 18) + ((blk1 & 63) << 12);
#pragma unroll
            for (int i = 0; i < 8; ++i) u4[i] = src[base1 + (i << 8) + lof];
        }
        // r1: m=(E0,E1,E10,E11,E12) -> RY q19,q18,q9,q8,q7
        RYT_(csl, 1, 19); RYT_(csl, 2, 18); RYT_(csl, 4, 9); RYT_(csl, 8, 8); RYT_(csl, 16, 7);
        { int w1x = (t & 31) ^ ((t >> 5) & 1);
#pragma unroll
          for (int m = 0; m < 32; ++m) lds[(t << 5) | (m ^ w1x)] = v[m]; }
        __syncthreads();

        // r2: frag=(E2,E3,E4,E5,E6) -> RY q17,q16,q15,q14,q13
        { int tp = (t & 31) | (((t >> 5) & 1) << 10) | (((t >> 6) & 7) << 11);
          int mt = mixR(tp);
#pragma unroll
          for (int f = 0; f < 32; ++f) { int fc = f << 5; v[f] = lds[(tp | fc) ^ mt ^ mixR(fc)]; }
          RYT_(csl, 1, 17); RYT_(csl, 2, 16); RYT_(csl, 4, 15); RYT_(csl, 8, 14); RYT_(csl, 16, 13);
#pragma unroll
          for (int f = 0; f < 32; ++f) { int fc = f << 5; lds[(tp | fc) ^ mt ^ mixR(fc)] = v[f]; } }
        __syncthreads();

        // r3: p=(E6,E7,E8,E9,E13) -> RY q12(2),q11(4),q10(8),q6(16)
        { int tp = ((t & 1) << 2) | (((t >> 1) & 1) << 3) | (((t >> 2) & 1) << 4)
                 | (((t >> 3) & 1) << 5) | (((t >> 4) & 1) << 1) | (((t >> 5) & 1) << 0)
                 | (((t >> 6) & 7) << 6);
          int mt = mixR(tp);
#pragma unroll
          for (int p = 0; p < 32; ++p) { int fc = p << 9; v[p] = lds[(tp | fc) ^ mt ^ mixR(fc)]; }
          RYT_(csl, 2, 12); RYT_(csl, 4, 11); RYT_(csl, 8, 10); RYT_(csl, 16, 6);
          int sb = base + (((t >> 6) & 7) << 6) + (t & 63);
#pragma unroll
          for (int j = 0; j < 8; ++j)
            dst[sb + (j << 9)] = make_float4(v[4*j], v[4*j+1], v[4*j+2], v[4*j+3]); }
        if (cc == 0) SWAPIN_;
    }
}

// ---------------- Pass A: M -> P ----------------
template <bool FULL>
__global__ __launch_bounds__(512, 4) void pass_A(
    const float4* __restrict__ src, float4* __restrict__ dst,
    const float2* __restrict__ cs, int layer)
{
    __shared__ float lds[16384];
    const float2* csl = cs + layer * 20;
    int t = threadIdx.x;
    float v[32];
    float4 u4[8];

    int rg = ((t >> 3) & 7) << 12;
    {   int blk = blockIdx.x;
        int G = blk & 63, b = blk >> 6;
        int Gperm = ((G >> 2) & 1) | (((G >> 1) & 1) << 1) | ((G & 1) << 2) | (((G >> 3) & 7) << 3);
        int lb = (b << 18) + (((t >> 6) & 7) << 9) + (Gperm << 3) + (t & 7);
#pragma unroll
        for (int i = 0; i < 8; ++i) {
            float4 w = src[lb + (i << 15) + rg];
            v[4*i] = w.x; v[4*i+1] = w.y; v[4*i+2] = w.z; v[4*i+3] = w.w;
        } }

#pragma unroll
    for (int cc = 0; cc < 2; ++cc) {
        int blk = blockIdx.x + (cc << 9);
        int G = blk & 63, b = blk >> 6;
        if (cc == 0) {
            int blk1 = blockIdx.x + 512;
            int G1 = blk1 & 63, b1 = blk1 >> 6;
            int Gp1 = ((G1 >> 2) & 1) | (((G1 >> 1) & 1) << 1) | ((G1 & 1) << 2) | (((G1 >> 3) & 7) << 3);
            int lb1 = (b1 << 18) + (((t >> 6) & 7) << 9) + (Gp1 << 3) + (t & 7);
#pragma unroll
            for (int i = 0; i < 8; ++i) u4[i] = src[lb1 + (i << 15) + rg];
        }
        // r1: m=(E6,E7,E17,E18,E19): RY q0(16),q1(8),q2(4); FULL: q12(2),q13(1)
        RYT_(csl, 16, 0); RYT_(csl, 8, 1); RYT_(csl, 4, 2);
        if (FULL) { RYT_(csl, 2, 12); RYT_(csl, 1, 13); }
        { int w1x = (t & 31) ^ ((t >> 5) & 1) ^ (((t >> 6) & 1) << 3)
                  ^ (((t >> 7) & 1) << 4) ^ (((t >> 8) & 1) << 4);
#pragma unroll
          for (int m = 0; m < 32; ++m) lds[(t << 5) | (m ^ w1x)] = v[m]; }
        __syncthreads();

        // r2: frag=(E15,E16,E17,E18,E19): RY q4(1),q3(2); links (19,18)..(16,15)
        { int tp = (t & 3) | (((t >> 2) & 1) << 7) | (((t >> 3) & 1) << 11)
                 | (((t >> 4) & 1) << 12) | (((t >> 5) & 1) << 13) | (((t >> 6) & 1) << 5)
                 | (((t >> 7) & 1) << 6) | (((t >> 8) & 1) << 8);
          int mt = mixA(tp);
#pragma unroll
          for (int f = 0; f < 32; ++f) {
            int fc = ((f & 1) << 9) | (((f >> 1) & 1) << 10) | (((f >> 2) & 1) << 2)
                   | (((f >> 3) & 1) << 3) | (((f >> 4) & 1) << 4);
            v[f] = lds[(tp | fc) ^ mt ^ mixA(fc)]; }
          RYT_(csl, 1, 4); RYT_(csl, 2, 3);
          CX_(16, 8); CX_(8, 4); CX_(4, 2); CX_(2, 1);
#pragma unroll
          for (int f = 0; f < 32; ++f) {
            int fc = ((f & 1) << 9) | (((f >> 1) & 1) << 10) | (((f >> 2) & 1) << 2)
                   | (((f >> 3) & 1) << 3) | (((f >> 4) & 1) << 4);
            lds[(tp | fc) ^ mt ^ mixA(fc)] = v[f]; } }
        __syncthreads();

        // r3: frag=(E10,E11,E12,E13,E14): RY q5(16); FULL q6..q9
        { int tp = (t & 31) | (((t >> 5) & 1) << 9) | (((t >> 6) & 1) << 10)
                 | (((t >> 7) & 1) << 11) | (((t >> 8) & 1) << 12);
          int mt = mixA(tp);
#pragma unroll
          for (int f = 0; f < 32; ++f) {
            int fc = ((f & 1) << 5) | (((f >> 1) & 1) << 6) | (((f >> 2) & 1) << 7)
                   | (((f >> 3) & 1) << 13) | (((f >> 4) & 1) << 8);
            v[f] = lds[(tp | fc) ^ mt ^ mixA(fc)]; }
          RYT_(csl, 16, 5);
          if (FULL) { RYT_(csl, 8, 6); RYT_(csl, 4, 7); RYT_(csl, 2, 8); RYT_(csl, 1, 9); }
          CXI_((t >> 5) & 1, 16); CX_(16, 8); CX_(8, 4); CX_(4, 2); CX_(2, 1);
#pragma unroll
          for (int f = 0; f < 32; ++f) {
            int fc = ((f & 1) << 5) | (((f >> 1) & 1) << 6) | (((f >> 2) & 1) << 7)
                   | (((f >> 3) & 1) << 13) | (((f >> 4) & 1) << 8);
            lds[(tp | fc) ^ mt ^ mixA(fc)] = v[f]; } }
        __syncthreads();

        // r4: p=(E6,E13,E7,E8,E9): FULL RY q10(16),q11(8); chain tail
        { int tp = ((t & 1) << 8) | (((t >> 1) & 1) << 9) | (((t >> 2) & 1) << 10)
                 | (((t >> 3) & 1) << 6) | (((t >> 4) & 1) << 7) | (((t >> 5) & 1) << 2)
                 | (((t >> 6) & 1) << 5) | (((t >> 7) & 1) << 3) | (((t >> 8) & 1) << 4);
          int mt = mixA(tp);
#pragma unroll
          for (int p = 0; p < 32; ++p) {
            int fc = ((p & 1) << 0) | (((p >> 1) & 1) << 13) | (((p >> 2) & 1) << 1)
                   | (((p >> 3) & 1) << 11) | (((p >> 4) & 1) << 12);
            v[p] = lds[(tp | fc) ^ mt ^ mixA(fc)]; }
          if (FULL) { RYT_(csl, 16, 10); RYT_(csl, 8, 11); }
          CXI_((t >> 6) & 1, 16); CX_(16, 8); CX_(8, 4); CX_(4, 1);
          int sb = (b << 18) + (G << 12) + t;
#pragma unroll
          for (int j = 0; j < 8; ++j)
            dst[sb + (j << 9)] = make_float4(v[4*j], v[4*j+1], v[4*j+2], v[4*j+3]); }
        if (cc == 0) SWAPIN_;
    }
}

// ---------------- Pass F: P -> Q ----------------
template <bool LOWRY>
__global__ __launch_bounds__(512, 4) void pass_F(
    const float4* __restrict__ src, float4* __restrict__ dst,
    const float2* __restrict__ cs, int layer)
{
    __shared__ float lds[16384];
    const float2* csl  = cs + layer * 20;
    const float2* csl2 = cs + (layer + 1) * 20;
    int t = threadIdx.x;
    float v[32];
    float4 u4[8];

    {   int blk = blockIdx.x;
        int W = blk & 63, b = blk >> 6;
        int Wp = (((W >> 4) & 1) << 3) | (((W >> 5) & 1) << 4) | (((W >> 3) & 1) << 6)
               | ((W & 1) << 9) | (((W >> 1) & 1) << 10) | (((W >> 2) & 1) << 11);
        int lb = (((b << 6) | ((t >> 3) & 63)) << 12) + (t & 7) + Wp;
#pragma unroll
        for (int i = 0; i < 8; ++i) {
            float4 w = src[lb + ((i & 1) << 5) + (((i >> 1) & 1) << 7) + (((i >> 2) & 1) << 8)];
            v[4*i] = w.x; v[4*i+1] = w.y; v[4*i+2] = w.z; v[4*i+3] = w.w;
        } }

#pragma unroll
    for (int cc = 0; cc < 2; ++cc) {
        int blk = blockIdx.x + (cc << 9);
        if (cc == 0) {
            int blk1 = blockIdx.x + 512;
            int W1 = blk1 & 63, b1 = blk1 >> 6;
            int Wp1 = (((W1 >> 4) & 1) << 3) | (((W1 >> 5) & 1) << 4) | (((W1 >> 3) & 1) << 6)
                    | ((W1 & 1) << 9) | (((W1 >> 1) & 1) << 10) | (((W1 >> 2) & 1) << 11);
            int lb1 = (((b1 << 6) | ((t >> 3) & 63)) << 12) + (t & 7) + Wp1;
#pragma unroll
            for (int i = 0; i < 8; ++i)
                u4[i] = src[lb1 + ((i & 1) << 5) + (((i >> 1) & 1) << 7) + (((i >> 2) & 1) << 8)];
        }
        // r1: m=(E6,E13,E17,E18,E19): RY+1 q0,q1,q2,q6; links+1 (19,18),(18,17)
        RYT_(csl2, 16, 0); RYT_(csl2, 8, 1); RYT_(csl2, 4, 2); RYT_(csl2, 2, 6);
        CX_(16, 8); CX_(8, 4);
        { int w1x = (t & 31) ^ (((t >> 5) & 1) << 1) ^ (((t >> 6) & 1) << 2)
                  ^ (((t >> 7) & 1) << 3) ^ (((t >> 8) & 1) << 4);
#pragma unroll
          for (int m = 0; m < 32; ++m) lds[(t << 5) | (m ^ w1x)] = v[m]; }
        __syncthreads();

        // r2: frag=(E1,E2,E3,E4,E5): [LOWRY q14..q18]; links_l (6,5)[idx]..(2,1)
        { int tp = (t & 31) | (((t >> 5) & 1) << 8) | (((t >> 6) & 1) << 5)
                 | (((t >> 7) & 1) << 6) | (((t >> 8) & 1) << 7);
          int mt = mixF(tp);
#pragma unroll
          for (int f = 0; f < 32; ++f) { int fc = f << 9; v[f] = lds[(tp | fc) ^ mt ^ mixF(fc)]; }
          if (LOWRY) { RYT_(csl, 16, 14); RYT_(csl, 8, 15); RYT_(csl, 4, 16); RYT_(csl, 2, 17); RYT_(csl, 1, 18); }
          CXI_(t & 1, 16); CX_(16, 8); CX_(8, 4); CX_(4, 2); CX_(2, 1);
#pragma unroll
          for (int f = 0; f < 32; ++f) { int fc = f << 9; lds[(tp | fc) ^ mt ^ mixF(fc)] = v[f]; } }
        __syncthreads();

        // r3: p=(E0,E13,E14,E15,E16): [LOWRY q19]; link_l (1,0)[idx];
        //     RY+1 q3,q4,q5; links+1 (17,16)[idx],(16,15),(15,14),(14,13)
        { int tp = ((t & 1) << 12) | (((t >> 1) & 1) << 13) | (((t >> 2) & 1) << 0)
                 | (((t >> 3) & 1) << 9) | (((t >> 4) & 1) << 10) | (((t >> 5) & 1) << 11)
                 | (((t >> 6) & 1) << 2) | (((t >> 7) & 1) << 3) | (((t >> 8) & 1) << 4);
          int mt = mixF(tp);
#pragma unroll
          for (int p = 0; p < 32; ++p) {
            int fc = ((p & 1) << 8) | (((p >> 1) & 1) << 1) | (((p >> 2) & 1) << 5)
                   | (((p >> 3) & 1) << 6) | (((p >> 4) & 1) << 7);
            v[p] = lds[(tp | fc) ^ mt ^ mixF(fc)]; }
          if (LOWRY) { RYT_(csl, 1, 19); }
          CXI_((t >> 3) & 1, 1);
          RYT_(csl2, 16, 3); RYT_(csl2, 8, 4); RYT_(csl2, 4, 5);
          CXI_((t >> 6) & 1, 16); CX_(16, 8); CX_(8, 4); CX_(4, 2);
          int sb = (blk << 12) + t;
#pragma unroll
          for (int j = 0; j < 8; ++j)
            dst[sb + (j << 9)] = make_float4(v[4*j], v[4*j+1], v[4*j+2], v[4*j+3]); }
        if (cc == 0) SWAPIN_;
    }
}

// ---------------- Pass L: Q -> M (mid) or std+abs (fin) ----------------
template <bool FIN>
__global__ __launch_bounds__(512, 4) void pass_L(
    const float4* __restrict__ src, float4* __restrict__ dst,
    const float2* __restrict__ cs, int layer)
{
    __shared__ float lds[16384];
    const float2* csl = cs + layer * 20;
    int t = threadIdx.x;
    float v[32];
    float4 u4[8];

    {   int blk = blockIdx.x;
        int H = blk & 63, b = blk >> 6;
        int Hp = (((H >> 3) & 7) << 6) | ((H & 7) << 9);
        int rb = (b << 6) | ((t >> 6) & 7);
        int lo = Hp + (t & 63);
#pragma unroll
        for (int i = 0; i < 8; ++i) {
            float4 w = src[((rb | (i << 3)) << 12) + lo];
            v[4*i] = w.x; v[4*i+1] = w.y; v[4*i+2] = w.z; v[4*i+3] = w.w;
        } }

#pragma unroll
    for (int cc = 0; cc < 2; ++cc) {
        int blk = blockIdx.x + (cc << 9);
        if (cc == 0) {
            int blk1 = blockIdx.x + 512;
            int H1 = blk1 & 63, b1 = blk1 >> 6;
            int Hp1 = (((H1 >> 3) & 7) << 6) | ((H1 & 7) << 9);
            int rb1 = (b1 << 6) | ((t >> 6) & 7);
            int lo1 = Hp1 + (t & 63);
#pragma unroll
            for (int i = 0; i < 8; ++i) u4[i] = src[((rb1 | (i << 3)) << 12) + lo1];
        }
        // r1: m=(E0,E13,E10,E11,E12): RY q19(1),q9(4),q8(8),q7(16)
        RYT_(csl, 1, 19); RYT_(csl, 4, 9); RYT_(csl, 8, 8); RYT_(csl, 16, 7);
        { int w1x = (t & 31) ^ (((t >> 5) & 1) << 4) ^ (((t >> 6) & 1) << 2)
                  ^ (((t >> 7) & 1) << 3) ^ (((t >> 8) & 1) << 4);
#pragma unroll
          for (int m = 0; m < 32; ++m) lds[(t << 5) | (m ^ w1x)] = v[m]; }
        __syncthreads();

        // r2: frag=(E8,E9,E10,E11,E12): RY q10(2),q11(1); links (13,12)[idx]..(9,8)
        { int tp = (t & 3) | (((t >> 2) & 1) << 7) | (((t >> 3) & 1) << 8)
                 | (((t >> 4) & 1) << 9) | (((t >> 5) & 1) << 10) | (((t >> 6) & 1) << 5)
                 | (((t >> 7) & 1) << 6) | (((t >> 8) & 1) << 11);
          int mt = mixL(tp);
#pragma unroll
          for (int f = 0; f < 32; ++f) {
            int fc = ((f & 1) << 12) | (((f >> 1) & 1) << 13) | (((f >> 2) & 1) << 2)
                   | (((f >> 3) & 1) << 3) | (((f >> 4) & 1) << 4);
            v[f] = lds[(tp | fc) ^ mt ^ mixL(fc)]; }
          RYT_(csl, 2, 10); RYT_(csl, 1, 11);
          CXI_((t >> 1) & 1, 16); CX_(16, 8); CX_(8, 4); CX_(4, 2); CX_(2, 1);
#pragma unroll
          for (int f = 0; f < 32; ++f) {
            int fc = ((f & 1) << 12) | (((f >> 1) & 1) << 13) | (((f >> 2) & 1) << 2)
                   | (((f >> 3) & 1) << 3) | (((f >> 4) & 1) << 4);
            lds[(tp | fc) ^ mt ^ mixL(fc)] = v[f]; } }
        __syncthreads();

        // r3: frag=(E3,E4,E5,E6,E7): RY q12..q16; links (8,7)[idx]..(4,3)
        { int tp = (t & 31) | (((t >> 5) & 1) << 9) | (((t >> 6) & 1) << 8)
                 | (((t >> 7) & 1) << 12) | (((t >> 8) & 1) << 13);
          int mt = mixL(tp);
#pragma unroll
          for (int f = 0; f < 32; ++f) {
            int fc = ((f & 1) << 10) | (((f >> 1) & 1) << 5) | (((f >> 2) & 1) << 6)
                   | (((f >> 3) & 1) << 7) | (((f >> 4) & 1) << 11);
            v[f] = lds[(tp | fc) ^ mt ^ mixL(fc)]; }
          RYT_(csl, 16, 12); RYT_(csl, 8, 13); RYT_(csl, 4, 14); RYT_(csl, 2, 15); RYT_(csl, 1, 16);
          CXI_((t >> 7) & 1, 16); CX_(16, 8); CX_(8, 4); CX_(4, 2); CX_(2, 1);
#pragma unroll
          for (int f = 0; f < 32; ++f) {
            int fc = ((f & 1) << 10) | (((f >> 1) & 1) << 5) | (((f >> 2) & 1) << 6)
                   | (((f >> 3) & 1) << 7) | (((f >> 4) & 1) << 11);
            lds[(tp | fc) ^ mt ^ mixL(fc)] = v[f]; } }
        __syncthreads();

        // r4: u=(E0,E1,E2,E6,E7): RY q17(4),q18(2); links (3,2)[idx],(2,1),(1,0)
        { int tp;
          if (!FIN)
            tp = ((t & 1) << 2) | (((t >> 1) & 1) << 3) | (((t >> 2) & 1) << 4)
               | (((t >> 3) & 1) << 10) | (((t >> 4) & 1) << 5) | (((t >> 5) & 1) << 6)
               | (((t >> 6) & 1) << 1) | (((t >> 7) & 1) << 12) | (((t >> 8) & 1) << 13);
          else
            tp = ((t & 1) << 10) | (((t >> 1) & 1) << 5) | (((t >> 2) & 1) << 6)
               | (((t >> 3) & 1) << 12) | (((t >> 4) & 1) << 13) | (((t >> 5) & 1) << 2)
               | (((t >> 6) & 1) << 1) | (((t >> 7) & 1) << 3) | (((t >> 8) & 1) << 4);
          int mt = mixL(tp);
#pragma unroll
          for (int u = 0; u < 32; ++u) {
            int fc = ((u & 1) << 0) | (((u >> 1) & 1) << 8) | (((u >> 2) & 1) << 9)
                   | (((u >> 3) & 1) << 7) | (((u >> 4) & 1) << 11);
            v[u] = lds[(tp | fc) ^ mt ^ mixL(fc)]; }
          RYT_(csl, 4, 17); RYT_(csl, 2, 18);
          { int e3 = FIN ? (t & 1) : ((t >> 3) & 1);
            CXI_(e3, 4); }
          CX_(4, 2); CX_(2, 1);
          if (!FIN) {
            int sb = (blk << 12) + (t & 7) + (((t >> 3) & 7) << 6)
                   + (((t >> 7) & 3) << 9) + (((t >> 6) & 1) << 11);
#pragma unroll
            for (int g = 0; g < 8; ++g) {
              int bu = ((g >> 2) & 1) | (((g >> 1) & 1) << 1) | ((g & 1) << 2);
              dst[sb + (g << 3)] = make_float4(v[bu], v[bu | 8], v[bu | 16], v[bu | 24]);
            }
          } else {
            int sb = (blk << 12) + ((t & 7) << 1) + (((t >> 3) & 7) << 6)
                   + (((t >> 7) & 1) << 9) + (((t >> 8) & 1) << 10) + (((t >> 6) & 1) << 11);
#pragma unroll
            for (int g = 0; g < 8; ++g) {
              int bu = ((g & 1) << 2) | (((g >> 1) & 1) << 3) | (((g >> 2) & 1) << 4);
              dst[sb + (g & 1) + (((g >> 1) & 1) << 4) + (((g >> 2) & 1) << 5)] =
                make_float4(fabsf(v[bu]), fabsf(v[bu | 1]), fabsf(v[bu | 2]), fabsf(v[bu | 3]));
            }
          } }
        if (cc == 0) SWAPIN_;
    }
}

extern "C" void kernel_launch(void* const* d_in, const int* in_sizes, int n_in,
                              void* d_out, int out_size, void* d_ws, size_t ws_size,
                              hipStream_t stream) {
    const float* x     = (const float*)d_in[0];   // (16, 2^20) f32, standard layout
    const float* theta = (const float*)d_in[1];   // (80,) f32
    float2* cs = (float2*)d_ws;                   // 80 (cos,sin) pairs
    float4* wsS = (float4*)((char*)d_ws + 4096);  // 64 MB scratch state
    float4* out = (float4*)d_out;

    cs_kernel<<<1, 128, 0, stream>>>(theta, cs);

    dim3 grid(512), block(512);
    pass_R<<<grid, block, 0, stream>>>((const float4*)x, out, cs);            // L0 lo-RY
    pass_A<false><<<grid, block, 0, stream>>>(out, wsS, cs, 0);               // L0 hi
    pass_F<false><<<grid, block, 0, stream>>>(wsS, out, cs, 0);               // L0 lo-chain + L1 hi
    pass_L<false><<<grid, block, 0, stream>>>(out, wsS, cs, 1);               // L1 lo
    pass_A<true><<<grid, block, 0, stream>>>(wsS, out, cs, 2);                // L2 hi (full RY)
    pass_F<true><<<grid, block, 0, stream>>>(out, wsS, cs, 2);                // L2 lo + L3 hi
    pass_L<true><<<grid, block, 0, stream>>>(wsS, out, cs, 3);                // L3 lo + abs
}

// Round 6
// 402.007 us; speedup vs baseline: 1.3440x; 1.3440x over previous
//
#include <hip/hip_runtime.h>
#include <math.h>

// 20-qubit, 4-layer RY+CNOT-chain circuit, batch 16, purely-real f32 state.
// qubit q <-> element bit E(19-q). TWO fused passes via multi-layer pyramid:
//  P1 window q0..q13 (E19..E6): all RY_l(q<=13-l), CX_l(q,q+1) with q+1<=13-l.
//  P2 window q6..q19 (E13..E0): the remainder. Deferred gates commute
//  (disjoint qubits, verified per-pair). Intermediate buffer L is a
//  bit-permuted layout making P1 stores and P2 loads dense.
// L bit map (low->high): L0=E6 L1=E7 L2=E8 L3=E9 L4=E10 L5=E11 L6=E12 L7=E13
//  L8=E0 L9=E1 L10=E2 L11=E3 L12=E4 L13=E5 L14..19=E14..E19, then batch.

#define RYT_(TBL, MASK, IDX) { float2 _sc = (TBL)[(IDX)]; float _c = _sc.x, _s = _sc.y; \
  _Pragma("unroll") for (int _m = 0; _m < 32; ++_m) if (!(_m & (MASK))) { \
    float _a = v[_m], _b = v[_m | (MASK)]; \
    v[_m] = _c*_a - _s*_b; v[_m | (MASK)] = _s*_a + _c*_b; } }

#define CX_(CM, TM) { _Pragma("unroll") for (int _m = 0; _m < 32; ++_m) \
  if ((_m & (CM)) && !(_m & (TM))) { float _t = v[_m]; v[_m] = v[_m|(TM)]; v[_m|(TM)] = _t; } }

#define CXI_(COND, TM) { if (COND) { _Pragma("unroll") for (int _m = 0; _m < 32; ++_m) \
  if (!(_m & (TM))) { float _t = v[_m]; v[_m] = v[_m|(TM)]; v[_m|(TM)] = _t; } } }

__global__ void cs_kernel(const float* __restrict__ theta, float2* __restrict__ cs) {
    int i = threadIdx.x;
    if (i < 80) { float s, c; sincosf(theta[i] * 0.5f, &s, &c); cs[i] = make_float2(c, s); }
}

__device__ __forceinline__ int swb14(int x) { return x ^ (((x >> 5) ^ (x >> 10)) & 31); }

// ---------------- Pass 1: x (standard) -> L.  Window w_j = qubit q_j. ----------------
// Rounds (frag qubits): r1=[0..4] r2=[2..6] r3=[4..8] r4=[6..10] r5=[8..12] r6=[9..13].
// Thread-bit maps per round documented inline. 2 windows/block (E0 pair), 512 thr.
__global__ __launch_bounds__(512) void pass1(
    const float2* __restrict__ x2, float* __restrict__ L,
    const float2* __restrict__ cs)
{
    __shared__ float lds[16384];
    const int t = threadIdx.x;
    const int blk = blockIdx.x;                  // 512 blocks
    const int b = blk >> 5, idx5 = blk & 31;     // idx5 bit j = E(1+j)

    // r1 thread map: t0..t5 = w5..w10 (=E14..E9), t6..t8 = w11..w13 (=E8..E6)
    const int tbx = ((t&1)<<14)|((t&2)<<12)|((t&4)<<10)|((t&8)<<8)|((t&16)<<6)
                  | ((t&32)<<4)|((t&64)<<2)|(t&128)|((t&256)>>2);
    const float2* px = x2 + ((size_t)b << 19) + (tbx >> 1) + idx5;

    float v[32], u[32];
#pragma unroll
    for (int r = 0; r < 32; ++r) {               // reg bit j = q_j = E(19-j)
        int rv = ((r&1)<<4)|((r&2)<<2)|(r&4)|((r&8)>>2)|((r&16)>>4);
        float2 d = px[rv << 14];
        v[r] = d.x; u[r] = d.y;                  // E0=0 / E0=1 windows
    }

    // LDS bases (canonical addr = w identity; swizzle = XOR-fold into low5)
    const int A1 = (t<<5) ^ ((t ^ (t>>5)) & 31);
    const int B2 = swb14((t&3)  | (((t>>2)&15)<<7) | (((t>>6)&7)<<11));
    const int B3 = swb14((t&15) | (((t>>4)&3)<<9)  | (((t>>6)&7)<<11));
    const int B4 = swb14((t&63) | (((t>>6)&7)<<11));
    const int B5 = swb14((t&255)| (((t>>8)&1)<<13));
    const int tb6 = ((t&1)<<8)|((t&2)<<6)|((t&4)<<4)|((t&8)<<2)|(t&16)
                  | ((t&32)>>2)|((t&64)>>4)|((t&128)>>6)|((t&256)>>8);
    const int B6 = swb14(tb6);

    // store base: r6 lanes (w8,w7,w6)->L5..7, (w5,w4,w3)->L14..16, wv (w2,w1,w0)->L17..19
    float* Lout = L + (((t&7)<<5) | (((t>>3)&7)<<14) | (((t>>6)&7)<<17))
                    + (idx5 << 9) + ((size_t)b << 20);

    for (int cc = 0; cc < 2; ++cc) {
        if (cc == 1) {
#pragma unroll
            for (int r = 0; r < 32; ++r) v[r] = u[r];
        }
        // ---- r1: frag q0..q4 (mask q_j = 1<<j) ----
        RYT_(cs,1,0); RYT_(cs,2,1); RYT_(cs,4,2); RYT_(cs,8,3); RYT_(cs,16,4);
        CX_(1,2); CX_(2,4); CX_(4,8); CX_(8,16);
        RYT_(cs,1,20); RYT_(cs,2,21); RYT_(cs,4,22); RYT_(cs,8,23);
        CX_(1,2); CX_(2,4); CX_(4,8);
        RYT_(cs,1,40); RYT_(cs,2,41); RYT_(cs,4,42);
        CX_(1,2); CX_(2,4);
        RYT_(cs,1,60); RYT_(cs,2,61);
        CX_(1,2);
#pragma unroll
        for (int r = 0; r < 32; ++r) lds[A1 ^ r] = v[r];          // intra-wave
#pragma unroll
        for (int r = 0; r < 32; ++r) v[r] = lds[B2 ^ ((r<<2) ^ (r>>3))];

        // ---- r2: frag q2..q6 (q2=1,q3=2,q4=4,q5=8,q6=16) ----
        RYT_(cs,8,5); RYT_(cs,16,6);
        CX_(4,8); CX_(8,16);
        RYT_(cs,4,24); RYT_(cs,8,25);
        CX_(2,4); CX_(4,8);
        RYT_(cs,2,43); RYT_(cs,4,44);
        CX_(1,2); CX_(2,4);
        RYT_(cs,1,62); RYT_(cs,2,63);
        CXI_((t>>1)&1, 1); CX_(1,2);
#pragma unroll
        for (int r = 0; r < 32; ++r) lds[B2 ^ ((r<<2) ^ (r>>3))] = v[r];
#pragma unroll
        for (int r = 0; r < 32; ++r) v[r] = lds[B3 ^ ((r<<4) ^ (r>>1))];

        // ---- r3: frag q4..q8 ----
        RYT_(cs,8,7); RYT_(cs,16,8);
        CX_(4,8); CX_(8,16);
        RYT_(cs,4,26); RYT_(cs,8,27);
        CX_(2,4); CX_(4,8);
        RYT_(cs,2,45); RYT_(cs,4,46);
        CX_(1,2); CX_(2,4);
        RYT_(cs,1,64); RYT_(cs,2,65);
        CXI_((t>>3)&1, 1); CX_(1,2);
#pragma unroll
        for (int r = 0; r < 32; ++r) lds[B3 ^ ((r<<4) ^ (r>>1))] = v[r];
#pragma unroll
        for (int r = 0; r < 32; ++r) v[r] = lds[B4 ^ ((r<<6) ^ ((r<<1)&31) ^ (r>>4))];

        // ---- r4: frag q6..q10 ----
        RYT_(cs,8,9); RYT_(cs,16,10);
        CX_(4,8); CX_(8,16);
        RYT_(cs,4,28); RYT_(cs,8,29);
        CX_(2,4); CX_(4,8);
        RYT_(cs,2,47); RYT_(cs,4,48);
        CX_(1,2); CX_(2,4);
        RYT_(cs,1,66); RYT_(cs,2,67);
        CXI_((t>>5)&1, 1); CX_(1,2);
#pragma unroll
        for (int r = 0; r < 32; ++r) lds[B4 ^ ((r<<6) ^ ((r<<1)&31) ^ (r>>4))] = v[r];
        __syncthreads();                         // cross-wave transpose
#pragma unroll
        for (int r = 0; r < 32; ++r) v[r] = lds[B5 ^ ((r<<8) ^ ((r<<3)&31) ^ (r>>2))];

        // ---- r5: frag q8..q12 ----
        RYT_(cs,8,11); RYT_(cs,16,12);
        CX_(4,8); CX_(8,16);
        RYT_(cs,4,30); RYT_(cs,8,31);
        CX_(2,4); CX_(4,8);
        RYT_(cs,2,49); RYT_(cs,4,50);
        CX_(1,2); CX_(2,4);
        RYT_(cs,1,68); RYT_(cs,2,69);
        CXI_((t>>7)&1, 1); CX_(1,2);
#pragma unroll
        for (int r = 0; r < 32; ++r) lds[B5 ^ ((r<<8) ^ ((r<<3)&31) ^ (r>>2))] = v[r];
        __syncthreads();                         // cross-wave transpose
#pragma unroll
        for (int r = 0; r < 32; ++r) {
            int rv = ((r&1)<<4)|((r&2)<<2)|(r&4)|((r&8)>>2)|((r&16)>>4);
            v[r] = lds[B6 ^ ((rv<<9) ^ ((rv<<4)&31) ^ (rv>>1))];
        }

        // ---- r6: frag (q13,q12,q11,q10,q9) -> masks 1,2,4,8,16 ----
        RYT_(cs,1,13);  CX_(2,1);
        RYT_(cs,2,32);  CX_(4,2);
        RYT_(cs,4,51);  CX_(8,4);
        RYT_(cs,8,70);  CX_(16,8);

        // store: thread-contiguous 128B; E0 (window select) -> L8
#pragma unroll
        for (int j = 0; j < 8; ++j)
            *(float4*)(Lout + (cc<<8) + 4*j) =
                make_float4(v[4*j], v[4*j+1], v[4*j+2], v[4*j+3]);
        __syncthreads();                         // protect LDS reuse across windows
    }
}

// ---------------- Pass 2: L -> out (standard, abs). Wave-autonomous. ----------------
// Active window q9..q19 (11 bits) per wave; q6..q8 (E13..E11) are index bits.
// Rounds: r1 frag (q13,q12,q11,q14,q15); r2 (q13..q17); r3 (q15..q19).
__global__ __launch_bounds__(256) void pass2(
    const float* __restrict__ L, float* __restrict__ out,
    const float2* __restrict__ cs)
{
    __shared__ float lds[8192];
    const int t = threadIdx.x;
    const int wq = t >> 6;
    const int widx = blockIdx.x * 4 + wq;        // 8192 waves
    const int b = widx >> 9, e9 = widx & 511;    // e9 bit j = E(11+j)
    const int sb = wq << 11;                     // private LDS slice

    // load: lanes t0->L3 t1->L4 t2->L8 t3->L9 t4->L10 t5->L11; i bits E8,E5,E4
    const float* Lin = L + (((t&3)<<3) | (((t>>2)&15)<<8) | ((e9&7)<<5)
                            | (((e9>>3)&63)<<14)) + ((size_t)b << 20);
    float v[32];
#pragma unroll
    for (int i = 0; i < 8; ++i) {
        float4 w = *(const float4*)(Lin + (((i&1)<<2) + (((i>>1)&1)<<13) + (((i>>2)&1)<<12)));
        v[4*i+0] = w.x; v[4*i+1] = w.y; v[4*i+2] = w.z; v[4*i+3] = w.w;
    }

    // ---- r1: frag (q13,q12,q11,q14,q15) -> masks 1,2,4,8,16 ----
    RYT_(cs,8,14); RYT_(cs,16,15);
    CX_(1,8); CX_(8,16);
    RYT_(cs,1,33); RYT_(cs,8,34);
    CX_(2,1); CX_(1,8);
    RYT_(cs,2,52); RYT_(cs,1,53);
    CX_(4,2); CX_(2,1);
    RYT_(cs,4,71); RYT_(cs,2,72);
    CXI_(t&1, 4); CX_(4,2);

    // LDS canonical local bit j = q(9+j). r1: t0->bit1 t1->bit0 t2->bit10 t3->bit9 t4->bit8 t5->bit7
    {
        const int tb1 = ((t&1)<<1)|((t&2)>>1)|((t&4)<<8)|((t&8)<<6)|((t&16)<<4)|((t&32)<<2);
        const int C1 = tb1 ^ (((tb1>>5) ^ (tb1>>10)) & 31);
#pragma unroll
        for (int r = 0; r < 32; ++r) {
            int cb = ((r&1)<<4)|((r&2)<<2)|(r&4)|((r&8)<<2)|((r&16)<<2);  // frag->bits 4,3,2,5,6
            lds[sb + (C1 ^ cb ^ ((r>>3)&3))] = v[r];
        }
    }
    {
        const int tb2 = (t&15) | ((t&16)<<5) | ((t&32)<<5);
        const int C2 = tb2 ^ (((tb2>>5) ^ (tb2>>10)) & 31);
#pragma unroll
        for (int r = 0; r < 32; ++r) v[r] = lds[sb + (C2 ^ ((r<<4) ^ (r>>1)))];

        // ---- r2: frag q13..q17 -> masks 1,2,4,8,16 ----
        RYT_(cs,8,16); RYT_(cs,16,17);
        CX_(4,8); CX_(8,16);
        RYT_(cs,4,35); RYT_(cs,8,36);
        CX_(2,4); CX_(4,8);
        RYT_(cs,2,54); RYT_(cs,4,55);
        CX_(1,2); CX_(2,4);
        RYT_(cs,1,73); RYT_(cs,2,74);
        CXI_((t>>3)&1, 1); CX_(1,2);

#pragma unroll
        for (int r = 0; r < 32; ++r) lds[sb + (C2 ^ ((r<<4) ^ (r>>1)))] = v[r];
    }
    {
        const int tb3 = t & 63;
        const int C3 = tb3 ^ ((tb3>>5) & 31);
#pragma unroll
        for (int r = 0; r < 32; ++r) v[r] = lds[sb + (C3 ^ ((r<<6) ^ ((r<<1)&31) ^ (r>>4)))];
    }

    // ---- r3: frag q15..q19 -> masks 1,2,4,8,16 ----
    RYT_(cs,8,18); RYT_(cs,16,19);
    CX_(4,8); CX_(8,16);
    RYT_(cs,4,37); RYT_(cs,8,38); RYT_(cs,16,39);
    CX_(2,4); CX_(4,8); CX_(8,16);
    RYT_(cs,2,56); RYT_(cs,4,57); RYT_(cs,8,58); RYT_(cs,16,59);
    CX_(1,2); CX_(2,4); CX_(4,8); CX_(8,16);
    RYT_(cs,1,75); RYT_(cs,2,76); RYT_(cs,4,77); RYT_(cs,8,78); RYT_(cs,16,79);
    CXI_((t>>5)&1, 1); CX_(1,2); CX_(2,4); CX_(4,8); CX_(8,16);

    // store standard layout + abs: lanes q9..q14 -> E10..E5; thread owns 32 consec floats
    float* po = out + (((t&1)<<10)|((t&2)<<8)|((t&4)<<6)|((t&8)<<4)|((t&16)<<2)|(t&32))
                    + ((e9&7)<<11) + (((e9>>3)&63)<<14) + ((size_t)b << 20);
#pragma unroll
    for (int i = 0; i < 8; ++i) {
        *(float4*)(po + (((i&1)<<4) + ((i&2)<<2) + (i&4))) =
            make_float4(fabsf(v[i]), fabsf(v[i|16]), fabsf(v[i|8]), fabsf(v[i|24]));
    }
}

extern "C" void kernel_launch(void* const* d_in, const int* in_sizes, int n_in,
                              void* d_out, int out_size, void* d_ws, size_t ws_size,
                              hipStream_t stream) {
    const float* x     = (const float*)d_in[0];   // (16, 2^20) f32, standard layout
    const float* theta = (const float*)d_in[1];   // (80,) f32
    float2* cs = (float2*)d_ws;                   // 80 (cos,sin) pairs
    float*  Lb = (float*)((char*)d_ws + 4096);    // 64 MB permuted intermediate

    cs_kernel<<<1, 128, 0, stream>>>(theta, cs);
    pass1<<<512, 512, 0, stream>>>((const float2*)x, Lb, cs);
    pass2<<<2048, 256, 0, stream>>>(Lb, (float*)d_out, cs);
}